// Round 9
// baseline (15618.787 us; speedup 1.0000x reference)
//
#include <hip/hip_runtime.h>
#include <math.h>

// Problem constants (match reference)
#define BB   32
#define LSEQ 512
#define DD   512
#define HH   512
#define G2H  1024
#define K3H  1536

// Scan: 16 groups x 32 WGs (group = blk&15). Group g owns batch rows 2g,2g+1.
// WG slot s (0..31) owns c/innov/K cols jz=16s..16s+15, kmid cols jm=48s..+47.
// 256 thr = 4 waves; wave q owns col quarter (4 c-cols, 12 kmid cols) x both
// rows. Sync = ONE-HOP u8 tag barrier: producer publishes data (sc0sc1),
// drains vmcnt, stores 1 tag BYTE; consumers poll the group's 32-byte tag
// blob with TWO dwordx4 pollers per WG -> 64 reqs/line/round-trip = R6's
// proven-safe MALL hot-line rate, but with no master hop (R8's 256/line and
// R7's 4096/line both queued the MALL and inflated the chain).
// u8 generation wrap is safe: inter-WG skew is bounded by 1 stage << 128
// (windowed compare (u8)(tag-want) < 128).
// Whh slice (32KB) in LDS; kW1/kW2 as f16-packed GLOBAL arrays (3MB, L2-
// resident, prefetched into registers BEFORE the poll so L2 latency hides
// behind the spin).
#define NG      16
#define GWG     32
#define TSTRIDE 1024   // u32 stride between group tag lines (4KB, channel spread)

typedef unsigned int u32;
typedef _Float16 half2_t __attribute__((ext_vector_type(2)));
typedef u32 v4u __attribute__((ext_vector_type(4)));

// ---- coherence-point memory ops ----
__device__ __forceinline__ void mload4(v4u& d, const u32* p) {
  asm volatile("global_load_dwordx4 %0, %1, off sc1" : "=v"(d) : "v"(p));
}
__device__ __forceinline__ void mstore(u32* p, u32 v) {
  asm volatile("global_store_dword %0, %1, off sc0 sc1" :: "v"(p), "v"(v)
               : "memory");
}
__device__ __forceinline__ void mstoreb(void* p, u32 v) {
  asm volatile("global_store_byte %0, %1, off sc0 sc1" :: "v"(p), "v"(v)
               : "memory");
}
__device__ __forceinline__ void vmwait(v4u& a) {
  asm volatile("s_waitcnt vmcnt(0)" : "+v"(a) :: "memory");
}

__device__ __forceinline__ float dot2acc(u32 a, u32 b, float acc) {
#if __has_builtin(__builtin_amdgcn_fdot2)
  return __builtin_amdgcn_fdot2(__builtin_bit_cast(half2_t, a),
                                __builtin_bit_cast(half2_t, b), acc, false);
#else
  half2_t ha = __builtin_bit_cast(half2_t, a);
  half2_t hb = __builtin_bit_cast(half2_t, b);
  return acc + (float)ha[0] * (float)hb[0] + (float)ha[1] * (float)hb[1];
#endif
}
__device__ __forceinline__ float dotq(v4u a, v4u b, float acc) {
  acc = dot2acc(a.x, b.x, acc);
  acc = dot2acc(a.y, b.y, acc);
  acc = dot2acc(a.z, b.z, acc);
  acc = dot2acc(a.w, b.w, acc);
  return acc;
}
__device__ __forceinline__ u32 pkf16(float a, float b) {
#if __has_builtin(__builtin_amdgcn_cvt_pkrtz)
  return __builtin_bit_cast(u32, __builtin_amdgcn_cvt_pkrtz(a, b));
#else
  half2_t h; h[0] = (_Float16)a; h[1] = (_Float16)b;
  return __builtin_bit_cast(u32, h);
#endif
}

// In-register shuffle reduction trees (value for index lane&(M-1)).
template<int M> struct TreeC {
  static __device__ __forceinline__ void run(float* a, int lane, int d) {
    const bool hi = (lane & d) != 0;
#pragma unroll
    for (int i = 0; i < M / 2; ++i) {
      float mine  = hi ? a[2 * i + 1] : a[2 * i];
      float yours = hi ? a[2 * i]     : a[2 * i + 1];
      a[i] = mine + __shfl_xor(yours, d, 64);
    }
    TreeC<M / 2>::run(a, lane, d << 1);
  }
};
template<> struct TreeC<1> {
  static __device__ __forceinline__ void run(float*, int, int) {}
};
template<int M>
__device__ __forceinline__ float tree_reduce(float* a, int lane) {
  TreeC<M>::run(a, lane, 1);
  float v = a[0];
#pragma unroll
  for (int d = M; d <= 32; d <<= 1) v += __shfl_xor(v, d, 64);
  return v;
}

// one-hop u8 tag wait: 2 pollers (tid 0,1), each one dwordx4 = 16 tags.
// Skips own byte (own tag store may still be in flight).
__device__ __forceinline__ void poll8(const u32* tgg, u32 gen, int tid, int s) {
  if (tid < 2) {
    const u32 want = gen & 0xFFu;
    const u32* p = tgg + tid * 4;
    const int own = s - tid * 16;   // own byte index within this chunk, or OOR
    for (;;) {
      v4u t; mload4(t, p); vmwait(t);
      u32 bad = 0;
#pragma unroll
      for (int w = 0; w < 4; ++w) {
        u32 x = t[w];
#pragma unroll
        for (int b = 0; b < 4; ++b) {
          int idx = w * 4 + b;
          u32 tag = (x >> (8 * b)) & 0xFFu;
          if (idx != own) bad |= (tag - want) & 0x80u;  // ready iff (u8)(tag-want)<128
        }
      }
      if (!bad) break;
    }
  }
  __syncthreads();
}

// drain this wave's outstanding global stores, then WG-sync
__device__ __forceinline__ void publish_fence() {
  asm volatile("s_waitcnt vmcnt(0)" ::: "memory");
  __syncthreads();
}

// ---------------------------------------------------------------------------
// RMSNorm: one 256-thread WG per row of 512.
// ---------------------------------------------------------------------------
__global__ __launch_bounds__(256)
void rmsnorm_kernel(const float* __restrict__ x, const float* __restrict__ w,
                    float* __restrict__ y)
{
  __shared__ float redl[256];
  const long row = blockIdx.x;
  const int t = threadIdx.x;
  const float* xr = x + row * DD;
  float v0 = xr[t], v1 = xr[t + 256];
  redl[t] = v0 * v0 + v1 * v1;
  __syncthreads();
  for (int off = 128; off > 0; off >>= 1) {
    if (t < off) redl[t] += redl[t + off];
    __syncthreads();
  }
  float scale = rsqrtf(redl[0] * (1.0f / 512.0f) + 1e-5f);
  float* yr = y + row * DD;
  yr[t]       = v0 * scale * w[t];
  yr[t + 256] = v1 * scale * w[t + 256];
}

// ---------------------------------------------------------------------------
// fp32 tiled GEMM: C[M,N] = A[M,K] @ B[K,N] (+ bias[n]), all row-major.
// ---------------------------------------------------------------------------
__global__ __launch_bounds__(256)
void gemm_fp32(const float* __restrict__ A, const float* __restrict__ B,
               const float* __restrict__ bias, float* __restrict__ C,
               int M, int N, int K)
{
  __shared__ float As[16][68];
  __shared__ float Bs[16][64];
  const int t  = threadIdx.x;
  const int tx = t & 15, ty = t >> 4;
  const long m0 = (long)blockIdx.x * 64;
  const long n0 = (long)blockIdx.y * 64;
  const int ar = t >> 2, ac = (t & 3) * 4;
  const int bk = t >> 4, bn = (t & 15) * 4;
  float acc[4][4] = {{0.f}};

  for (int k0 = 0; k0 < K; k0 += 16) {
    float4 av = *(const float4*)(A + (m0 + ar) * K + k0 + ac);
    float4 bv = *(const float4*)(B + (long)(k0 + bk) * N + n0 + bn);
    As[ac + 0][ar] = av.x; As[ac + 1][ar] = av.y;
    As[ac + 2][ar] = av.z; As[ac + 3][ar] = av.w;
    *(float4*)&Bs[bk][bn] = bv;
    __syncthreads();
#pragma unroll
    for (int kk = 0; kk < 16; ++kk) {
      float4 a = *(const float4*)&As[kk][ty * 4];
      float4 b = *(const float4*)&Bs[kk][tx * 4];
      acc[0][0] = fmaf(a.x, b.x, acc[0][0]); acc[0][1] = fmaf(a.x, b.y, acc[0][1]);
      acc[0][2] = fmaf(a.x, b.z, acc[0][2]); acc[0][3] = fmaf(a.x, b.w, acc[0][3]);
      acc[1][0] = fmaf(a.y, b.x, acc[1][0]); acc[1][1] = fmaf(a.y, b.y, acc[1][1]);
      acc[1][2] = fmaf(a.y, b.z, acc[1][2]); acc[1][3] = fmaf(a.y, b.w, acc[1][3]);
      acc[2][0] = fmaf(a.z, b.x, acc[2][0]); acc[2][1] = fmaf(a.z, b.y, acc[2][1]);
      acc[2][2] = fmaf(a.z, b.z, acc[2][2]); acc[2][3] = fmaf(a.z, b.w, acc[2][3]);
      acc[3][0] = fmaf(a.w, b.x, acc[3][0]); acc[3][1] = fmaf(a.w, b.y, acc[3][1]);
      acc[3][2] = fmaf(a.w, b.z, acc[3][2]); acc[3][3] = fmaf(a.w, b.w, acc[3][3]);
    }
    __syncthreads();
  }
  float4 bb = make_float4(0.f, 0.f, 0.f, 0.f);
  if (bias) bb = *(const float4*)(bias + n0 + tx * 4);
#pragma unroll
  for (int i = 0; i < 4; ++i) {
    float4 o;
    o.x = acc[i][0] + bb.x; o.y = acc[i][1] + bb.y;
    o.z = acc[i][2] + bb.z; o.w = acc[i][3] + bb.w;
    *(float4*)(C + (m0 + ty * 4 + i) * N + n0 + tx * 4) = o;
  }
}

// ---------------------------------------------------------------------------
// Prep: pack kW1/kW2 fp32 -> f16 pairs, col-major-by-pairs for the scan.
// kw1p[col*256 + p] = (kW1[2p][col], kW1[2p+1][col]), col<1536, p<256
// kw2p[col*768 + p] = (kW2[2p][col], kW2[2p+1][col]), col<512,  p<768
// ---------------------------------------------------------------------------
__global__ __launch_bounds__(256)
void pack_kw1(const float* __restrict__ kW1, u32* __restrict__ kw1p)
{
  int p = blockIdx.x;   // 0..255
  for (int col = threadIdx.x; col < K3H; col += 256)
    kw1p[(size_t)col * 256 + p] = pkf16(kW1[(size_t)(2 * p) * K3H + col],
                                        kW1[(size_t)(2 * p + 1) * K3H + col]);
}
__global__ __launch_bounds__(256)
void pack_kw2(const float* __restrict__ kW2, u32* __restrict__ kw2p)
{
  int p = blockIdx.x;   // 0..767
  for (int col = threadIdx.x; col < HH; col += 256)
    kw2p[(size_t)col * 768 + p] = pkf16(kW2[(size_t)(2 * p) * HH + col],
                                        kW2[(size_t)(2 * p + 1) * HH + col]);
}

// ---------------------------------------------------------------------------
// Persistent scan: 512 WGs x 256 thr, 38 KB static LDS (2 WGs/CU).
// State (row r=(lane>>2)&1, col jz+4q+(lane&3)) lives in lanes<8 of wave q.
// ---------------------------------------------------------------------------
__global__ __launch_bounds__(256)
void scan_kernel(const float* __restrict__ gx,
                 const float* __restrict__ Whh, const float* __restrict__ bhh,
                 const float* __restrict__ loglam,
                 const u32* __restrict__ kw1p, const float* __restrict__ kb1,
                 const u32* __restrict__ kw2p, const float* __restrict__ kb2,
                 u32* __restrict__ cpk, u32* __restrict__ ipk,
                 u32* __restrict__ kpk, u32* __restrict__ tags,
                 float* __restrict__ hs)
{
  const int blk  = blockIdx.x;
  const int g    = blk & 15;        // group (rows 2g, 2g+1)
  const int s    = blk >> 4;        // slot 0..31
  const int tid  = threadIdx.x;
  const int q    = tid >> 6;        // wave 0..3
  const int lane = tid & 63;
  const int jz   = s * 16;
  const int jm   = s * 48;

  __shared__ u32 whh[32 * 256];     // 32 KB: 16 z-cols + 16 m-cols, f16 pairs
  __shared__ u32 stg[2 * 768];      //  6 KB comm staging

  // ---- one-time Whh staging (fp32 -> f16 pairs) ----
  for (int idx = tid; idx < 32 * 256; idx += 256) {
    int c = idx >> 8, p = idx & 255;
    int gcol = (c < 16) ? (jz + c) : (512 + jz + (c - 16));
    whh[idx] = pkf16(Whh[(size_t)(2 * p) * G2H + gcol],
                     Whh[(size_t)(2 * p + 1) * G2H + gcol]);
  }

  // state mapping: lanes<8 of each wave: r=(lane>>2)&1, ci=lane&3
  const int ci = lane & 3;
  const int r  = (lane >> 2) & 1;
  const int colA = jz + 4 * q + ci;
  const int rowA = 2 * g + r;
  const float Ab   = 1.f - expf(loglam[colA]);
  const float bz   = bhh[colA];
  const float bm   = bhh[512 + colA];
  const float kb2c = kb2[colA];
  int c12 = lane & 15; if (c12 > 11) c12 = 11;
  const float kb1v = kb1[jm + 12 * q + c12];
  const size_t hsoff = (size_t)rowA * LSEQ * HH + colA;
  const size_t gxoff = (size_t)rowA * LSEQ * G2H + colA;

  u32* tgg = tags + g * TSTRIDE;

  // zero this WG's initial c slice (8 pairs x 2 rows), publish tag gen 1
  if (tid < 16) {
    int rr = tid >> 3, j = tid & 7;
    mstore(cpk + (size_t)(2 * g + rr) * 256 + 8 * s + j, 0u);
  }
  publish_fence();
  if (tid == 0) mstoreb((char*)tgg + s, 1u);

  float A_own = 0.f, c_own = 0.f, M_own = 0.f, I_own = 0.f, s_own = 1.f;

  for (int it = 0; it <= LSEQ; ++it) {
    const u32 base = 3u * (u32)it;

    // gx prefetch (cached, read-once)
    float gxz = 0.f, gxm = 0.f;
    if (lane < 8 && it < LSEQ) {
      gxz = gx[gxoff + (size_t)it * G2H];
      gxm = gx[gxoff + (size_t)it * G2H + 512];
    }

    // ---- S1: wait c(it) -> stage -> s, g = h@W_hh, innov ----
    poll8(tgg, base + 1, tid, s);
    if (tid < 128) {
      int rr = tid >> 6, off = (tid & 63) * 4;
      v4u t; mload4(t, cpk + (size_t)(2 * g + rr) * 256 + off); vmwait(t);
      *(v4u*)(stg + rr * 256 + off) = t;
    }
    __syncthreads();
    v4u cv0 = *(const v4u*)(stg + lane * 4);
    v4u cv1 = *(const v4u*)(stg + 256 + lane * 4);
    float a2[2] = { dotq(cv0, cv0, 0.f), dotq(cv1, cv1, 0.f) };
    float ssv = tree_reduce<2>(a2, lane);       // idx = lane&1 = row
    float a16[16];
#pragma unroll
    for (int zm = 0; zm < 2; ++zm)
#pragma unroll
      for (int cc = 0; cc < 4; ++cc) {
        v4u w = *(const v4u*)(whh + (zm * 16 + 4 * q + cc) * 256 + lane * 4);
        a16[0 * 8 + zm * 4 + cc] = dotq(cv0, w, 0.f);
        a16[1 * 8 + zm * 4 + cc] = dotq(cv1, w, 0.f);
      }
    float g16 = tree_reduce<16>(a16, lane);     // idx = r*8 + zm*4 + cc
    float sq = __shfl(ssv, r, 64);
    float s_loc = fminf(1.f, 10.f * rsqrtf(sq + 1e-6f));
    if (lane < 8 && it >= 1)
      hs[hsoff + (size_t)(it - 1) * HH] = s_loc * c_own;
    if (it == LSEQ) break;
    float gz = __shfl(g16, r * 8 + ci, 64);
    float gm = __shfl(g16, r * 8 + 4 + ci, 64);
    float gzv = gz * s_loc + gxz + bz;
    float gmv = gm * s_loc + gxm + bm;
    float Mv = tanhf(gmv);
    float iv = gzv - A_own * (s_loc * c_own) - Mv;
    if (lane < 8) { M_own = Mv; I_own = iv; s_own = s_loc; }
    float ivn = __shfl(iv, lane + 1, 64);
    if (lane < 8 && !(lane & 1))
      mstore(ipk + (size_t)rowA * 256 + 8 * s + 2 * q + (ci >> 1), pkf16(iv, ivn));
    publish_fence();
    if (tid == 0) mstoreb((char*)tgg + s, base + 2);

    // ---- S2: prefetch kW1 (L2) -> wait innov -> stage -> kmid ----
    v4u w1v[12];
#pragma unroll
    for (int cc = 0; cc < 12; ++cc)
      w1v[cc] = *(const v4u*)(kw1p + (size_t)(jm + 12 * q + cc) * 256 + lane * 4);
    poll8(tgg, base + 2, tid, s);
    if (tid < 128) {
      int rr = tid >> 6, off = (tid & 63) * 4;
      v4u t; mload4(t, ipk + (size_t)(2 * g + rr) * 256 + off); vmwait(t);
      *(v4u*)(stg + rr * 256 + off) = t;
    }
    __syncthreads();
    v4u iv0 = *(const v4u*)(stg + lane * 4);
    v4u iv1 = *(const v4u*)(stg + 256 + lane * 4);
    float a32[32];
#pragma unroll
    for (int i = 0; i < 32; ++i) a32[i] = 0.f;
#pragma unroll
    for (int cc = 0; cc < 12; ++cc) {
      a32[cc]      = dotq(iv0, w1v[cc], 0.f);
      a32[16 + cc] = dotq(iv1, w1v[cc], 0.f);
    }
    float t32 = tree_reduce<32>(a32, lane);     // idx = r*16 + cc
    float kvb = t32 + kb1v;
    float gl = 0.5f * kvb * (1.f + erff(kvb * 0.7071067811865476f));
    float gln = __shfl(gl, lane + 1, 64);
    if (lane < 32 && (lane & 15) < 12 && !(lane & 1)) {
      int rr = lane >> 4, cc = lane & 15;
      mstore(kpk + (size_t)(2 * g + rr) * 768 + 24 * s + 6 * q + (cc >> 1),
             pkf16(gl, gln));
    }
    publish_fence();
    if (tid == 0) mstoreb((char*)tgg + s, base + 3);

    // ---- S3: prefetch kW2 (L2) -> wait kmid -> stage -> K ; c update ----
    v4u w2v[4][3];
#pragma unroll
    for (int cc = 0; cc < 4; ++cc)
#pragma unroll
      for (int j = 0; j < 3; ++j)
        w2v[cc][j] = *(const v4u*)(kw2p + (size_t)(jz + 4 * q + cc) * 768 +
                                   j * 256 + lane * 4);
    poll8(tgg, base + 3, tid, s);
    {
      int rr0 = tid / 192, off0 = (tid % 192) * 4;
      v4u t0; mload4(t0, kpk + (size_t)(2 * g + rr0) * 768 + off0);
      v4u t1;
      if (tid < 128) {
        int off1 = ((256 + tid) % 192) * 4;
        mload4(t1, kpk + (size_t)(2 * g + 1) * 768 + off1);
      }
      vmwait(t0);
      *(v4u*)(stg + rr0 * 768 + off0) = t0;
      if (tid < 128) {
        int off1 = ((256 + tid) % 192) * 4;
        vmwait(t1);
        *(v4u*)(stg + 768 + off1) = t1;
      }
    }
    __syncthreads();
    v4u kv0[3], kv1[3];
#pragma unroll
    for (int j = 0; j < 3; ++j) {
      kv0[j] = *(const v4u*)(stg + j * 256 + lane * 4);
      kv1[j] = *(const v4u*)(stg + 768 + j * 256 + lane * 4);
    }
    float a8[8];
#pragma unroll
    for (int cc = 0; cc < 4; ++cc) {
      float acc0 = 0.f, acc1 = 0.f;
#pragma unroll
      for (int j = 0; j < 3; ++j) {
        acc0 = dotq(kv0[j], w2v[cc][j], acc0);
        acc1 = dotq(kv1[j], w2v[cc][j], acc1);
      }
      a8[cc] = acc0; a8[4 + cc] = acc1;
    }
    float kr = tree_reduce<8>(a8, lane);        // idx = r*4 + cc = own lane<8
    float Kv = tanhf(kr + kb2c) * 0.5f;
    float An = Ab * (1.f - Kv * Kv);
    float cn = An * (s_own * c_own) + Kv * I_own + M_own;
    if (lane < 8) { A_own = An; c_own = cn; }
    float cnn = __shfl(cn, lane + 1, 64);
    if (lane < 8 && !(lane & 1))
      mstore(cpk + (size_t)rowA * 256 + 8 * s + 2 * q + (ci >> 1), pkf16(cn, cnn));
    publish_fence();
    if (tid == 0) mstoreb((char*)tgg + s, base + 4);
  }
}

// ---------------------------------------------------------------------------
// Workspace layout (bytes):
//   [0, 32M)    xn (reused as hs)
//   [32M, 96M)  gx
//   [96M,128M)  xmid
//   [128M, ..)  cpk 32K | ipk 32K | kpk 96K | tags 64K
// kw1p/kw2p (3MB f16-packed weights) live in d_out — dead until the final
// layer-2 GEMM overwrites it (stream-ordered after both scans consume them).
// ---------------------------------------------------------------------------
extern "C" void kernel_launch(void* const* d_in, const int* in_sizes, int n_in,
                              void* d_out, int out_size, void* d_ws, size_t ws_size,
                              hipStream_t stream) {
  const float* x      = (const float*)d_in[0];
  const float* norm_w = (const float*)d_in[1];
  const float* W_ih   = (const float*)d_in[2];
  const float* b_ih   = (const float*)d_in[3];
  const float* W_hh   = (const float*)d_in[4];
  const float* b_hh   = (const float*)d_in[5];
  const float* loglam = (const float*)d_in[6];
  const float* kW1    = (const float*)d_in[7];
  const float* kb1    = (const float*)d_in[8];
  const float* kW2    = (const float*)d_in[9];
  const float* kb2    = (const float*)d_in[10];
  const float* Wo     = (const float*)d_in[11];
  float* out = (float*)d_out;

  char* ws = (char*)d_ws;
  float* xn   = (float*)(ws);
  float* gxb  = (float*)(ws + (size_t)33554432);
  float* xmid = (float*)(ws + (size_t)100663296);
  u32* cpk   = (u32*)(ws + (size_t)134217728);
  u32* ipk   = cpk + 8192;
  u32* kpk   = ipk + 8192;
  u32* tags  = kpk + 24576;            // NG * TSTRIDE u32 = 64 KB
  u32* kw1p  = (u32*)d_out;            // 1.5 MB
  u32* kw2p  = kw1p + 393216;          // 1.5 MB
  float* hs = xn;

  for (int l = 0; l < 2; ++l) {
    const float* xin = l ? (const float*)xmid : x;
    float* cout = l ? out : xmid;

    rmsnorm_kernel<<<BB * LSEQ, 256, 0, stream>>>(xin, norm_w, xn);

    gemm_fp32<<<dim3(256, 16), 256, 0, stream>>>(
        xn, W_ih + (size_t)l * DD * G2H, b_ih + (size_t)l * G2H, gxb,
        BB * LSEQ, G2H, DD);

    hipMemsetAsync(tags, 0, (size_t)NG * TSTRIDE * sizeof(u32), stream);
    pack_kw1<<<256, 256, 0, stream>>>(kW1 + (size_t)l * HH * K3H, kw1p);
    pack_kw2<<<768, 256, 0, stream>>>(kW2 + (size_t)l * K3H * HH, kw2p);

    scan_kernel<<<NG * GWG, 256, 0, stream>>>(
        gxb,
        W_hh + (size_t)l * HH * G2H, b_hh + (size_t)l * G2H,
        loglam + (size_t)l * HH,
        kw1p, kb1 + (size_t)l * K3H,
        kw2p, kb2 + (size_t)l * HH,
        cpk, ipk, kpk, tags, hs);

    gemm_fp32<<<dim3(256, 8), 256, 0, stream>>>(
        hs, Wo + (size_t)l * HH * DD, nullptr, cout,
        BB * LSEQ, DD, HH);
  }
}